// Round 20
// baseline (295.075 us; speedup 1.0000x reference)
//
#include <hip/hip_runtime.h>
#include <math.h>

// Problem constants: T=131072, D_IN=1024, NE=64, top_k=2
constexpr int T_TOKENS = 131072;
constexpr int D        = 1024;
constexpr float EPS_GAP = 1e-3f;   // flag threshold (bf16-split err ~1e-5 RMS)

typedef __attribute__((ext_vector_type(8))) short bf16x8;
typedef __attribute__((ext_vector_type(4))) float f32x4;
typedef __bf16 bf16v8 __attribute__((ext_vector_type(8)));
typedef float  f32v8  __attribute__((ext_vector_type(8)));

// split 8 fp32 into two bf16 planes (RNE): f ~= p0 + p1
__device__ __forceinline__ void split2(const float4 lo, const float4 hi,
                                       bf16x8& p0, bf16x8& p1) {
    f32v8 f = {lo.x, lo.y, lo.z, lo.w, hi.x, hi.y, hi.z, hi.w};
    bf16v8 h0 = __builtin_convertvector(f, bf16v8);
    f32v8 back = __builtin_convertvector(h0, f32v8);
    bf16v8 h1 = __builtin_convertvector(f - back, bf16v8);
    p0 = __builtin_bit_cast(bf16x8, h0);
    p1 = __builtin_bit_cast(bf16x8, h1);
}

// ---- Kernel 0: pre-split W into fragment-layout bf16 planes (256 KB) ------
// wpl[g*512 + (c*2+p)*64 + l] = plane_p( W[c*16 + (l&15)][g*32 + (l>>4)*8 .. +8] )
__global__ void prep_w(const float* __restrict__ W, bf16x8* __restrict__ wpl) {
    const int g = blockIdx.x;          // 0..31 (K window of 32)
    const int c = threadIdx.x >> 6;    // 0..3
    const int l = threadIdx.x & 63;
    const int e  = c * 16 + (l & 15);
    const int k0 = g * 32 + (l >> 4) * 8;
    const float4 lo = *(const float4*)(W + (long)e * D + k0);
    const float4 hi = *(const float4*)(W + (long)e * D + k0 + 4);
    bf16x8 p0, p1; split2(lo, hi, p0, p1);
    const int base = ((g * 4 + c) * 2) * 64 + l;
    wpl[base]      = p0;
    wpl[base + 64] = p1;
}

// ---- Kernel 1: K-split MFMA router with one-shot contiguous block staging --
// 8192 blocks x 256 thr (4 waves). Block = 16 tokens; wave w owns K-window
// [256w, 256w+256). Stage = 64 x 1KB global_load_lds covering ONE contiguous
// 64KB x-region per block (page-perfect, few fat streams). One vmcnt(0) per
// block; all compute from LDS. K-reduce via LDS partials + one __syncthreads
// (issued when VMEM is already drained). Wave 0 does the epilogue.
__global__ __launch_bounds__(256, 2)
void router_mfma(const float* __restrict__ x, const bf16x8* __restrict__ wpl,
                 float* __restrict__ out, unsigned* __restrict__ wcnt,
                 unsigned* __restrict__ wlist, unsigned cap)
{
    __shared__ __align__(16) char lds[4][16][1024];   // 64 KB: [wave][row][K-window]

    const int tid = threadIdx.x;
    const int wv  = tid >> 6;
    const int l   = tid & 63;
    const int lg  = l >> 4;       // k-octet
    const int lr  = l & 15;       // token row / expert within ctile
    const long t0 = (long)blockIdx.x * 16;
    const int swz = (lr & 7) << 4;
    const char* xb = (const char*)x;

    // ---- stage: 16 rows x 1KB (this wave's K strip), XOR-preswizzled src ----
#pragma unroll
    for (int i = 0; i < 16; ++i) {
        const char* src = xb + (t0 + i) * 4096L + wv * 1024
                          + ((l * 16) ^ ((i & 7) << 4));
        char* dst = &lds[wv][i][0];
        __builtin_amdgcn_global_load_lds(
            (const __attribute__((address_space(1))) void*)src,
            (__attribute__((address_space(3))) void*)dst, 16, 0, 0);
    }
    asm volatile("s_waitcnt vmcnt(0)" ::: "memory");
    __builtin_amdgcn_sched_barrier(0);

    f32x4 acc[4];
#pragma unroll
    for (int c = 0; c < 4; ++c) acc[c] = f32x4{0.f, 0.f, 0.f, 0.f};

    // ---- compute: 8 chunks of K=32 within this wave's window ----
#pragma unroll
    for (int kk = 0; kk < 8; ++kk) {
        const int g = wv * 8 + kk;          // global K window id
        bf16x8 w[8];
#pragma unroll
        for (int q = 0; q < 8; ++q)
            w[q] = wpl[(size_t)g * 512 + q * 64 + l];
        const char* rowp = &lds[wv][lr][0];
        const int c0 = kk * 128 + lg * 32;
        const float4 lo = *(const float4*)(rowp + (c0 ^ swz));
        const float4 hi = *(const float4*)(rowp + ((c0 + 16) ^ swz));
        bf16x8 a0, a1;
        split2(lo, hi, a0, a1);
#pragma unroll
        for (int c = 0; c < 4; ++c) {
            acc[c] = __builtin_amdgcn_mfma_f32_16x16x32_bf16(a0, w[c*2+0], acc[c], 0, 0, 0);
            acc[c] = __builtin_amdgcn_mfma_f32_16x16x32_bf16(a1, w[c*2+0], acc[c], 0, 0, 0);
            acc[c] = __builtin_amdgcn_mfma_f32_16x16x32_bf16(a0, w[c*2+1], acc[c], 0, 0, 0);
        }
    }

    // ---- K-reduce: waves store partials in their own region; wave 0 sums ----
    {
        char* pw = &lds[wv][0][0];
#pragma unroll
        for (int c = 0; c < 4; ++c)
            *(f32x4*)(pw + l * 64 + c * 16) = acc[c];
    }
    __syncthreads();     // VMEM already drained; pure LDS visibility barrier
    if (wv != 0) return;

#pragma unroll
    for (int w2 = 1; w2 < 4; ++w2) {
        const char* pr = &lds[w2][0][0];
#pragma unroll
        for (int c = 0; c < 4; ++c)
            acc[c] += *(const f32x4*)(pr + l * 64 + c * 16);
    }

    // ---- epilogue: top-3 per token, provisional write + gap-flag ----
    // C/D: col = lane&15 (expert in ctile), row = (lane>>4)*4 + reg (token)
#pragma unroll
    for (int r = 0; r < 4; ++r) {
        float v1 = acc[0][r]; int i1 = lr;
        float v2 = -INFINITY; int i2 = 1 << 20;
        float v3 = -INFINITY;
#pragma unroll
        for (int c = 1; c < 4; ++c) {
            const float v = acc[c][r]; const int e = lr + 16 * c;
            if (v > v1)      { v3 = v2; v2 = v1; i2 = i1; v1 = v; i1 = e; }
            else if (v > v2) { v3 = v2; v2 = v;  i2 = e; }
            else if (v > v3) { v3 = v; }
        }
#pragma unroll
        for (int m = 8; m >= 1; m >>= 1) {
            const float ov1 = __shfl_xor(v1, m);
            const int   oi1 = __shfl_xor(i1, m);
            const float ov2 = __shfl_xor(v2, m);
            const int   oi2 = __shfl_xor(i2, m);
            const float ov3 = __shfl_xor(v3, m);
            const bool tv = v1 >= ov1;
            const float x2 = tv ? v2 : ov2, x3 = tv ? v3 : ov3;
            const float y1 = tv ? ov1 : v1, y2 = tv ? ov2 : v2;
            const float nv3 = (x2 >= y1) ? fmaxf(x3, y1) : fmaxf(x2, y2);
            const bool aw = (ov1 > v1) || (ov1 == v1 && oi1 < i1);
            const float nv1 = aw ? ov1 : v1; const int ni1 = aw ? oi1 : i1;
            const float c1v = aw ? v1  : ov1; const int c1i = aw ? i1  : oi1;
            const float c2v = aw ? ov2 : v2;  const int c2i = aw ? oi2 : i2;
            const bool bw = (c1v > c2v) || (c1v == c2v && c1i < c2i);
            v1 = nv1; i1 = ni1;
            v2 = bw ? c1v : c2v; i2 = bw ? c1i : c2i;
            v3 = nv3;
        }
        if (lr == 0) {
            const long t = t0 + lg * 4 + r;
            const float e  = expf(v2 - v1);
            const float dn = 1.0f + e;
            out[t * 2 + 0] = (float)i1;
            out[t * 2 + 1] = (float)i2;
            out[(long)T_TOKENS * 2 + t * 2 + 0] = 1.0f / dn;
            out[(long)T_TOKENS * 2 + t * 2 + 1] = e / dn;
            if (v1 - v2 < EPS_GAP || v2 - v3 < EPS_GAP) {
                const unsigned p = atomicAdd(wcnt, 1u);
                if (p < cap) wlist[p] = (unsigned)t;
            }
        }
    }
}

// ---- Kernel 2: exact-chain fixup, 4 waves/token (one per OpenBLAS panel) --
// Exact OpenBLAS-SKYLAKEX chain (verified R7+): panels 320/320/192/192,
// ascending-k fp32 FMA chain per panel, sequential rounded folds.
__global__ __launch_bounds__(256)
void router_fixup(const float* __restrict__ x, const float* __restrict__ W,
                  float* __restrict__ out, const unsigned* __restrict__ wcnt,
                  const unsigned* __restrict__ wlist, unsigned cap)
{
    __shared__ float ps[4][64];
    unsigned cnt = wcnt[0]; if (cnt > cap) cnt = cap;
    const int wv = threadIdx.x >> 6;   // panel id
    const int l  = threadIdx.x & 63;   // expert
    const int kb = (wv == 0) ? 0 : (wv == 1) ? 320 : (wv == 2) ? 640 : 832;
    const int ke = (wv == 0) ? 320 : (wv == 1) ? 640 : (wv == 2) ? 832 : 1024;

    for (unsigned it = blockIdx.x; it < cnt; it += gridDim.x) {
        const long t = (long)wlist[it];
        const float* xr = x + t * (long)D;
        const float* wr = W + (long)l * D;
        float accP = 0.f;
#pragma unroll 4
        for (int k = kb; k < ke; k += 4) {
            const float4 xv = *(const float4*)(xr + k);
            const float4 wvv = *(const float4*)(wr + k);
            accP = fmaf(xv.x, wvv.x, accP);
            accP = fmaf(xv.y, wvv.y, accP);
            accP = fmaf(xv.z, wvv.z, accP);
            accP = fmaf(xv.w, wvv.w, accP);
        }
        ps[wv][l] = accP;
        __syncthreads();
        if (wv == 0) {
            const float accT = __fadd_rn(__fadd_rn(__fadd_rn(ps[0][l], ps[1][l]), ps[2][l]), ps[3][l]);
            float v1 = accT; int i1 = l;
            float v2 = -INFINITY; int i2 = 1 << 20;
#pragma unroll
            for (int m = 32; m >= 1; m >>= 1) {
                const float ov1 = __shfl_xor(v1, m);
                const int   oi1 = __shfl_xor(i1, m);
                const float ov2 = __shfl_xor(v2, m);
                const int   oi2 = __shfl_xor(i2, m);
                const bool aw = (ov1 > v1) || (ov1 == v1 && oi1 < i1);
                const float nv1 = aw ? ov1 : v1; const int ni1 = aw ? oi1 : i1;
                const float c1v = aw ? v1  : ov1; const int c1i = aw ? i1  : oi1;
                const float c2v = aw ? ov2 : v2;  const int c2i = aw ? oi2 : i2;
                const bool bw = (c1v > c2v) || (c1v == c2v && c1i < c2i);
                v1 = nv1; i1 = ni1;
                v2 = bw ? c1v : c2v; i2 = bw ? c1i : c2i;
            }
            if (l == 0) {
                const float e  = expf(v2 - v1);
                const float dn = 1.0f + e;
                out[t * 2 + 0] = (float)i1;
                out[t * 2 + 1] = (float)i2;
                out[(long)T_TOKENS * 2 + t * 2 + 0] = 1.0f / dn;
                out[(long)T_TOKENS * 2 + t * 2 + 1] = e / dn;
            }
        }
        __syncthreads();
    }
}

extern "C" void kernel_launch(void* const* d_in, const int* in_sizes, int n_in,
                              void* d_out, int out_size, void* d_ws, size_t ws_size,
                              hipStream_t stream) {
    const float* x = (const float*)d_in[0];
    const float* W = (const float*)d_in[1];
    float* out = (float*)d_out;

    // workspace layout: [0,64) wcnt | [1024, 1024+256K) W frag planes | wlist
    unsigned* wcnt  = (unsigned*)d_ws;
    bf16x8*   wpl   = (bf16x8*)((char*)d_ws + 1024);
    unsigned* wlist = (unsigned*)((char*)d_ws + 1024 + 262144);
    size_t rem = (ws_size - 1024 - 262144) / 4;
    unsigned cap = (unsigned)(rem > (1u << 22) ? (1u << 22) : rem);

    (void)hipMemsetAsync(d_ws, 0, 64, stream);
    prep_w<<<dim3(32), dim3(256), 0, stream>>>(W, wpl);
    router_mfma<<<dim3(T_TOKENS / 16), dim3(256), 0, stream>>>(x, wpl, out, wcnt, wlist, cap);
    router_fixup<<<dim3(512), dim3(256), 0, stream>>>(x, W, out, wcnt, wlist, cap);
}

// Round 21
// 198.109 us; speedup vs baseline: 1.4895x; 1.4895x over previous
//
#include <hip/hip_runtime.h>
#include <math.h>

// Problem constants: T=131072, D_IN=1024, NE=64, top_k=2
constexpr int T_TOKENS = 131072;
constexpr int D        = 1024;
constexpr float EPS_GAP = 2e-4f;   // flag threshold (>=14 sigma of ~1.4e-5 RMS split err)

typedef __attribute__((ext_vector_type(8))) short bf16x8;
typedef __attribute__((ext_vector_type(4))) float f32x4;
typedef __bf16 bf16v8 __attribute__((ext_vector_type(8)));
typedef float  f32v8  __attribute__((ext_vector_type(8)));

// split 8 fp32 into two bf16 planes (RNE): f ~= p0 + p1
__device__ __forceinline__ void split2(const float4 lo, const float4 hi,
                                       bf16x8& p0, bf16x8& p1) {
    f32v8 f = {lo.x, lo.y, lo.z, lo.w, hi.x, hi.y, hi.z, hi.w};
    bf16v8 h0 = __builtin_convertvector(f, bf16v8);
    f32v8 back = __builtin_convertvector(h0, f32v8);
    bf16v8 h1 = __builtin_convertvector(f - back, bf16v8);
    p0 = __builtin_bit_cast(bf16x8, h0);
    p1 = __builtin_bit_cast(bf16x8, h1);
}

// ---- Kernel 0: pre-split W into fragment-layout bf16 planes (256 KB) ------
// wpl[g*512 + (c*2+p)*64 + l] = plane_p( W[c*16 + (l&15)][g*32 + (l>>4)*8 .. +8] )
__global__ void prep_w(const float* __restrict__ W, bf16x8* __restrict__ wpl) {
    const int g = blockIdx.x;          // 0..31 (K window of 32)
    const int c = threadIdx.x >> 6;    // 0..3
    const int l = threadIdx.x & 63;
    const int e  = c * 16 + (l & 15);
    const int k0 = g * 32 + (l >> 4) * 8;
    const float4 lo = *(const float4*)(W + (long)e * D + k0);
    const float4 hi = *(const float4*)(W + (long)e * D + k0 + 4);
    bf16x8 p0, p1; split2(lo, hi, p0, p1);
    const int base = ((g * 4 + c) * 2) * 64 + l;
    wpl[base]      = p0;
    wpl[base + 64] = p1;
}

// ---- Kernel 1: zero-barrier MFMA router, 512B runs, 32-token waves --------
// 2048 blocks x 128 thr (2 independent waves; NO __syncthreads).
// Wave = 32 tokens x 64 experts. Chunk = KSTEP=128 (512B contiguous per row):
// 16 x 1KB global_load_lds into wave-private double buffers (64KB/block ->
// 2 blocks/CU). Per-chunk issue order: W(s) 32 frag loads FIRST, stage(s+1)
// SECOND, then s_waitcnt vmcnt(16) -- retires W(s)+stage(s) exactly while
// stage(s+1) (16KB) stays in flight. In-order vmcnt audited.
__global__ __launch_bounds__(128)
void router_mfma(const float* __restrict__ x, const bf16x8* __restrict__ wpl,
                 float* __restrict__ out, unsigned* __restrict__ wcnt,
                 unsigned* __restrict__ wlist, unsigned cap)
{
    __shared__ __align__(16) char Xs[2][2][16384];  // [wave][buf][32 rows x 512B]

    const int tid = threadIdx.x;
    const int wv  = tid >> 6;
    const int l   = tid & 63;
    const int lg  = l >> 4;       // k-octet
    const int lr  = l & 15;       // token row in tile / expert in ctile
    const long t0 = (long)blockIdx.x * 64 + wv * 32;
    const int swz = (lr & 7) << 4;
    const char* xb = (const char*)x;

    f32x4 acc[2][4];
#pragma unroll
    for (int a = 0; a < 2; ++a)
#pragma unroll
        for (int c = 0; c < 4; ++c) acc[a][c] = f32x4{0.f, 0.f, 0.f, 0.f};

    // staging: instr i covers rows 2i, 2i+1; lane l -> row 2i+(l>>5),
    // byte (l&31)*16 of the row's 512B window, XOR-preswizzled source.
#define STAGE(S, BUF)                                                          \
    {                                                                          \
        _Pragma("unroll")                                                      \
        for (int i = 0; i < 16; ++i) {                                         \
            const int rr = 2 * i + (l >> 5);                                   \
            const char* src = xb + (t0 + rr) * 4096L + (S) * 512               \
                              + (((l & 31) * 16) ^ ((rr & 7) << 4));           \
            char* dst = &Xs[wv][BUF][i * 1024];                                \
            __builtin_amdgcn_global_load_lds(                                  \
                (const __attribute__((address_space(1))) void*)src,            \
                (__attribute__((address_space(3))) void*)dst, 16, 0, 0);       \
        }                                                                      \
    }

    STAGE(0, 0);

#pragma unroll 1
    for (int s = 0; s < 8; ++s) {
        const int buf = s & 1;
        // 1. W fragments for this chunk's 4 k-windows (L1/L2-hot), FIRST
        bf16x8 w[4][8];
#pragma unroll
        for (int g = 0; g < 4; ++g)
#pragma unroll
            for (int q = 0; q < 8; ++q)
                w[g][q] = wpl[(size_t)(s * 4 + g) * 512 + q * 64 + l];
        // 2. issue next chunk's staging (clamped redundant on last iter)
        const int sn = (s + 1 < 8) ? s + 1 : 7;
        if (buf) { STAGE(sn, 0) } else { STAGE(sn, 1) }
        // 3. counted wait: outstanding = W(s):32 + stage(s+1):16 (stage(s)
        //    older, retired too) -> vmcnt(16) = stage(s+1) stays in flight
        asm volatile("s_waitcnt vmcnt(16)" ::: "memory");
        __builtin_amdgcn_sched_barrier(0);
        // 4. compute chunk s: 4 substeps of K=32, both 16-row tiles
        const char* ab = &Xs[wv][buf][0];
#pragma unroll
        for (int sub = 0; sub < 4; ++sub) {
            const int c0 = sub * 128 + lg * 32;
#pragma unroll
            for (int a = 0; a < 2; ++a) {
                const char* rowp = ab + (a * 16 + lr) * 512;
                const float4 lo = *(const float4*)(rowp + (c0 ^ swz));
                const float4 hi = *(const float4*)(rowp + ((c0 + 16) ^ swz));
                bf16x8 a0, a1;
                split2(lo, hi, a0, a1);
#pragma unroll
                for (int c = 0; c < 4; ++c) {
                    acc[a][c] = __builtin_amdgcn_mfma_f32_16x16x32_bf16(a0, w[sub][c*2+0], acc[a][c], 0, 0, 0);
                    acc[a][c] = __builtin_amdgcn_mfma_f32_16x16x32_bf16(a1, w[sub][c*2+0], acc[a][c], 0, 0, 0);
                    acc[a][c] = __builtin_amdgcn_mfma_f32_16x16x32_bf16(a0, w[sub][c*2+1], acc[a][c], 0, 0, 0);
                }
            }
        }
    }
#undef STAGE

    // ---- epilogue: top-3 per token, provisional write + gap-flag ----
    // C/D: col = lane&15 (expert in ctile), row = (lane>>4)*4 + reg (token)
#pragma unroll
    for (int a = 0; a < 2; ++a)
#pragma unroll
    for (int r = 0; r < 4; ++r) {
        float v1 = acc[a][0][r]; int i1 = lr;
        float v2 = -INFINITY;    int i2 = 1 << 20;
        float v3 = -INFINITY;
#pragma unroll
        for (int c = 1; c < 4; ++c) {
            const float v = acc[a][c][r]; const int e = lr + 16 * c;
            if (v > v1)      { v3 = v2; v2 = v1; i2 = i1; v1 = v; i1 = e; }
            else if (v > v2) { v3 = v2; v2 = v;  i2 = e; }
            else if (v > v3) { v3 = v; }
        }
#pragma unroll
        for (int m = 8; m >= 1; m >>= 1) {
            const float ov1 = __shfl_xor(v1, m);
            const int   oi1 = __shfl_xor(i1, m);
            const float ov2 = __shfl_xor(v2, m);
            const int   oi2 = __shfl_xor(i2, m);
            const float ov3 = __shfl_xor(v3, m);
            const bool tv = v1 >= ov1;
            const float x2 = tv ? v2 : ov2, x3 = tv ? v3 : ov3;
            const float y1 = tv ? ov1 : v1, y2 = tv ? ov2 : v2;
            const float nv3 = (x2 >= y1) ? fmaxf(x3, y1) : fmaxf(x2, y2);
            const bool aw = (ov1 > v1) || (ov1 == v1 && oi1 < i1);
            const float nv1 = aw ? ov1 : v1; const int ni1 = aw ? oi1 : i1;
            const float c1v = aw ? v1  : ov1; const int c1i = aw ? i1  : oi1;
            const float c2v = aw ? ov2 : v2;  const int c2i = aw ? oi2 : i2;
            const bool bw = (c1v > c2v) || (c1v == c2v && c1i < c2i);
            v1 = nv1; i1 = ni1;
            v2 = bw ? c1v : c2v; i2 = bw ? c1i : c2i;
            v3 = nv3;
        }
        if (lr == 0) {
            const long t = t0 + a * 16 + lg * 4 + r;
            const float e  = expf(v2 - v1);
            const float dn = 1.0f + e;
            out[t * 2 + 0] = (float)i1;
            out[t * 2 + 1] = (float)i2;
            out[(long)T_TOKENS * 2 + t * 2 + 0] = 1.0f / dn;
            out[(long)T_TOKENS * 2 + t * 2 + 1] = e / dn;
            if (v1 - v2 < EPS_GAP || v2 - v3 < EPS_GAP) {
                const unsigned p = atomicAdd(wcnt, 1u);
                if (p < cap) wlist[p] = (unsigned)t;
            }
        }
    }
}

// ---- Kernel 2: exact-chain fixup, 4 waves/token (one per OpenBLAS panel) --
// Exact OpenBLAS-SKYLAKEX chain (verified R7+): panels 320/320/192/192,
// ascending-k fp32 FMA chain per panel, sequential rounded folds.
__global__ __launch_bounds__(256)
void router_fixup(const float* __restrict__ x, const float* __restrict__ W,
                  float* __restrict__ out, const unsigned* __restrict__ wcnt,
                  const unsigned* __restrict__ wlist, unsigned cap)
{
    __shared__ float ps[4][64];
    unsigned cnt = wcnt[0]; if (cnt > cap) cnt = cap;
    const int wv = threadIdx.x >> 6;   // panel id
    const int l  = threadIdx.x & 63;   // expert
    const int kb = (wv == 0) ? 0 : (wv == 1) ? 320 : (wv == 2) ? 640 : 832;
    const int ke = (wv == 0) ? 320 : (wv == 1) ? 640 : (wv == 2) ? 832 : 1024;

    for (unsigned it = blockIdx.x; it < cnt; it += gridDim.x) {
        const long t = (long)wlist[it];
        const float* xr = x + t * (long)D;
        const float* wr = W + (long)l * D;
        float accP = 0.f;
#pragma unroll 4
        for (int k = kb; k < ke; k += 4) {
            const float4 xv = *(const float4*)(xr + k);
            const float4 wvv = *(const float4*)(wr + k);
            accP = fmaf(xv.x, wvv.x, accP);
            accP = fmaf(xv.y, wvv.y, accP);
            accP = fmaf(xv.z, wvv.z, accP);
            accP = fmaf(xv.w, wvv.w, accP);
        }
        ps[wv][l] = accP;
        __syncthreads();
        if (wv == 0) {
            const float accT = __fadd_rn(__fadd_rn(__fadd_rn(ps[0][l], ps[1][l]), ps[2][l]), ps[3][l]);
            float v1 = accT; int i1 = l;
            float v2 = -INFINITY; int i2 = 1 << 20;
#pragma unroll
            for (int m = 32; m >= 1; m >>= 1) {
                const float ov1 = __shfl_xor(v1, m);
                const int   oi1 = __shfl_xor(i1, m);
                const float ov2 = __shfl_xor(v2, m);
                const int   oi2 = __shfl_xor(i2, m);
                const bool aw = (ov1 > v1) || (ov1 == v1 && oi1 < i1);
                const float nv1 = aw ? ov1 : v1; const int ni1 = aw ? oi1 : i1;
                const float c1v = aw ? v1  : ov1; const int c1i = aw ? i1  : oi1;
                const float c2v = aw ? ov2 : v2;  const int c2i = aw ? oi2 : i2;
                const bool bw = (c1v > c2v) || (c1v == c2v && c1i < c2i);
                v1 = nv1; i1 = ni1;
                v2 = bw ? c1v : c2v; i2 = bw ? c1i : c2i;
            }
            if (l == 0) {
                const float e  = expf(v2 - v1);
                const float dn = 1.0f + e;
                out[t * 2 + 0] = (float)i1;
                out[t * 2 + 1] = (float)i2;
                out[(long)T_TOKENS * 2 + t * 2 + 0] = 1.0f / dn;
                out[(long)T_TOKENS * 2 + t * 2 + 1] = e / dn;
            }
        }
        __syncthreads();
    }
}

extern "C" void kernel_launch(void* const* d_in, const int* in_sizes, int n_in,
                              void* d_out, int out_size, void* d_ws, size_t ws_size,
                              hipStream_t stream) {
    const float* x = (const float*)d_in[0];
    const float* W = (const float*)d_in[1];
    float* out = (float*)d_out;

    // workspace layout: [0,64) wcnt | [1024, 1024+256K) W frag planes | wlist
    unsigned* wcnt  = (unsigned*)d_ws;
    bf16x8*   wpl   = (bf16x8*)((char*)d_ws + 1024);
    unsigned* wlist = (unsigned*)((char*)d_ws + 1024 + 262144);
    size_t rem = (ws_size - 1024 - 262144) / 4;
    unsigned cap = (unsigned)(rem > (1u << 22) ? (1u << 22) : rem);

    (void)hipMemsetAsync(d_ws, 0, 64, stream);
    prep_w<<<dim3(32), dim3(256), 0, stream>>>(W, wpl);
    router_mfma<<<dim3(T_TOKENS / 64), dim3(128), 0, stream>>>(x, wpl, out, wcnt, wlist, cap);
    router_fixup<<<dim3(512), dim3(256), 0, stream>>>(x, W, out, wcnt, wlist, cap);
}

// Round 22
// 162.437 us; speedup vs baseline: 1.8165x; 1.2196x over previous
//
#include <hip/hip_runtime.h>
#include <math.h>

// Problem constants: T=131072, D_IN=1024, NE=64, top_k=2
constexpr int T_TOKENS = 131072;
constexpr int D        = 1024;
constexpr float EPS_GAP = 2e-4f;   // flag threshold (>=14 sigma of ~1.4e-5 RMS split err)

typedef __attribute__((ext_vector_type(8))) short bf16x8;
typedef __attribute__((ext_vector_type(4))) float f32x4;
typedef __bf16 bf16v8 __attribute__((ext_vector_type(8)));
typedef float  f32v8  __attribute__((ext_vector_type(8)));

// split 8 fp32 into two bf16 planes (RNE): f ~= p0 + p1
__device__ __forceinline__ void split2(const float4 lo, const float4 hi,
                                       bf16x8& p0, bf16x8& p1) {
    f32v8 f = {lo.x, lo.y, lo.z, lo.w, hi.x, hi.y, hi.z, hi.w};
    bf16v8 h0 = __builtin_convertvector(f, bf16v8);
    f32v8 back = __builtin_convertvector(h0, f32v8);
    bf16v8 h1 = __builtin_convertvector(f - back, bf16v8);
    p0 = __builtin_bit_cast(bf16x8, h0);
    p1 = __builtin_bit_cast(bf16x8, h1);
}

// ---- Kernel 0: pre-split W into fragment-layout bf16 planes (256 KB) ------
// wpl[g*512 + (c*2+p)*64 + l] = plane_p( W[c*16 + (l&15)][g*32 + (l>>4)*8 .. +8] )
__global__ void prep_w(const float* __restrict__ W, bf16x8* __restrict__ wpl) {
    const int g = blockIdx.x;          // 0..31 (K window of 32)
    const int c = threadIdx.x >> 6;    // 0..3
    const int l = threadIdx.x & 63;
    const int e  = c * 16 + (l & 15);
    const int k0 = g * 32 + (l >> 4) * 8;
    const float4 lo = *(const float4*)(W + (long)e * D + k0);
    const float4 hi = *(const float4*)(W + (long)e * D + k0 + 4);
    bf16x8 p0, p1; split2(lo, hi, p0, p1);
    const int base = ((g * 4 + c) * 2) * 64 + l;
    wpl[base]      = p0;
    wpl[base + 64] = p1;
}

// ---- Kernel 1: wave-private LDS-staged MFMA router, counted-vmcnt sync ----
// 1024 blocks x 256 thr (4 waves, fully independent; NO __syncthreads).
// Wave = 32 tokens x 64 experts. A: 256B-contiguous-per-row chunks (KSTEP=64)
// staged via global_load_lds into wave-private double buffers; sync via
// s_waitcnt vmcnt(24) only (stage(s+1) stays in flight across compute).
// W: prep_w fragment planes, loads hoisted to iteration top so their
// compiler waits never drain the staging pipeline.
__global__ __launch_bounds__(256, 2)
void router_mfma(const float* __restrict__ x, const bf16x8* __restrict__ wpl,
                 float* __restrict__ out, unsigned* __restrict__ wcnt,
                 unsigned* __restrict__ wlist, unsigned cap)
{
    __shared__ __align__(16) char Xs[4][2][8192];   // [wave][buf][32 rows x 256B]

    const int tid = threadIdx.x;
    const int wv  = tid >> 6;
    const int l   = tid & 63;
    const int lg  = l >> 4;       // k-octet
    const int lr  = l & 15;       // A row within tile / expert within ctile
    const long t0 = (long)blockIdx.x * 128 + wv * 32;
    const int swz = (lr & 7) << 4;

    f32x4 acc[2][4];
#pragma unroll
    for (int a = 0; a < 2; ++a)
#pragma unroll
        for (int c = 0; c < 4; ++c) acc[a][c] = f32x4{0.f, 0.f, 0.f, 0.f};

    // staging geometry: instruction i covers rows 4i..4i+3; lane covers
    // bytes [(l&15)*16, +16) of row (4i + (l>>4))'s 256B chunk window.
    const int sil = (l & 15) * 16;
    const int sir = l >> 4;
    const char* xb = (const char*)x;

#define STAGE(S, BUF)                                                          \
    {                                                                          \
        _Pragma("unroll")                                                      \
        for (int i = 0; i < 8; ++i) {                                          \
            const int rr = 4 * i + sir;                                        \
            const char* src = xb + (t0 + rr) * 4096L + (S) * 256               \
                              + (sil ^ ((rr & 7) << 4));                       \
            char* dst = &Xs[wv][BUF][(4 * i + sir) * 0 + i * 1024];            \
            __builtin_amdgcn_global_load_lds(                                  \
                (const __attribute__((address_space(1))) void*)src,            \
                (__attribute__((address_space(3))) void*)dst, 16, 0, 0);       \
        }                                                                      \
    }

#define SUBSTEP(SUB, W)                                                        \
    {                                                                          \
        const int c0 = (SUB) * 128 + lg * 32;                                  \
        const float4 lo0 = *(const float4*)(wb + lr * 256 + ((c0) ^ swz));     \
        const float4 hi0 = *(const float4*)(wb + lr * 256 + ((c0 + 16) ^ swz));\
        const float4 lo1 = *(const float4*)(wb + (16 + lr) * 256 + ((c0) ^ swz));     \
        const float4 hi1 = *(const float4*)(wb + (16 + lr) * 256 + ((c0 + 16) ^ swz));\
        bf16x8 a00, a01, a10, a11;                                             \
        split2(lo0, hi0, a00, a01);                                            \
        split2(lo1, hi1, a10, a11);                                            \
        _Pragma("unroll")                                                      \
        for (int c = 0; c < 4; ++c) {                                          \
            acc[0][c] = __builtin_amdgcn_mfma_f32_16x16x32_bf16(a00, W[c*2+0], acc[0][c], 0, 0, 0); \
            acc[0][c] = __builtin_amdgcn_mfma_f32_16x16x32_bf16(a01, W[c*2+0], acc[0][c], 0, 0, 0); \
            acc[0][c] = __builtin_amdgcn_mfma_f32_16x16x32_bf16(a00, W[c*2+1], acc[0][c], 0, 0, 0); \
            acc[1][c] = __builtin_amdgcn_mfma_f32_16x16x32_bf16(a10, W[c*2+0], acc[1][c], 0, 0, 0); \
            acc[1][c] = __builtin_amdgcn_mfma_f32_16x16x32_bf16(a11, W[c*2+0], acc[1][c], 0, 0, 0); \
            acc[1][c] = __builtin_amdgcn_mfma_f32_16x16x32_bf16(a10, W[c*2+1], acc[1][c], 0, 0, 0); \
        }                                                                      \
    }

    STAGE(0, 0);

#pragma unroll 1
    for (int s = 0; s < 16; ++s) {
        const int buf = s & 1;
        // 1. W prefetch for substeps (g = 2s, 2s+1) -- BEFORE stage issue
        bf16x8 w0[8], w1[8];
#pragma unroll
        for (int c = 0; c < 4; ++c) {
            w0[c * 2 + 0] = wpl[(size_t)(2 * s) * 512 + (c * 2 + 0) * 64 + l];
            w0[c * 2 + 1] = wpl[(size_t)(2 * s) * 512 + (c * 2 + 1) * 64 + l];
            w1[c * 2 + 0] = wpl[(size_t)(2 * s + 1) * 512 + (c * 2 + 0) * 64 + l];
            w1[c * 2 + 1] = wpl[(size_t)(2 * s + 1) * 512 + (c * 2 + 1) * 64 + l];
        }
        // 2. issue next chunk's staging (clamped last iter; redundant, unread)
        const int sn = (s + 1 < 16) ? s + 1 : 15;
        if (buf) { STAGE(sn, 0) } else { STAGE(sn, 1) }
        // 3. chunk s staged?  outstanding <= W(16) + stage_next(8) = 24
        asm volatile("s_waitcnt vmcnt(24)" ::: "memory");
        __builtin_amdgcn_sched_barrier(0);
        // 4. compute chunk s (2 substeps of 32 k)
        const char* wb = &Xs[wv][buf][0];
        SUBSTEP(0, w0)
        SUBSTEP(1, w1)
    }
#undef SUBSTEP
#undef STAGE

    // ---- epilogue: top-3 per token, provisional write + gap-flag ----
    // C/D: col = lane&15 (expert in ctile), row = (lane>>4)*4 + reg (token)
#pragma unroll
    for (int a = 0; a < 2; ++a)
#pragma unroll
    for (int r = 0; r < 4; ++r) {
        float v1 = acc[a][0][r]; int i1 = lr;
        float v2 = -INFINITY;    int i2 = 1 << 20;
        float v3 = -INFINITY;
#pragma unroll
        for (int c = 1; c < 4; ++c) {
            const float v = acc[a][c][r]; const int e = lr + 16 * c;
            if (v > v1)      { v3 = v2; v2 = v1; i2 = i1; v1 = v; i1 = e; }
            else if (v > v2) { v3 = v2; v2 = v;  i2 = e; }
            else if (v > v3) { v3 = v; }
        }
#pragma unroll
        for (int m = 8; m >= 1; m >>= 1) {
            const float ov1 = __shfl_xor(v1, m);
            const int   oi1 = __shfl_xor(i1, m);
            const float ov2 = __shfl_xor(v2, m);
            const int   oi2 = __shfl_xor(i2, m);
            const float ov3 = __shfl_xor(v3, m);
            const bool tv = v1 >= ov1;
            const float x2 = tv ? v2 : ov2, x3 = tv ? v3 : ov3;
            const float y1 = tv ? ov1 : v1, y2 = tv ? ov2 : v2;
            const float nv3 = (x2 >= y1) ? fmaxf(x3, y1) : fmaxf(x2, y2);
            const bool aw = (ov1 > v1) || (ov1 == v1 && oi1 < i1);
            const float nv1 = aw ? ov1 : v1; const int ni1 = aw ? oi1 : i1;
            const float c1v = aw ? v1  : ov1; const int c1i = aw ? i1  : oi1;
            const float c2v = aw ? ov2 : v2;  const int c2i = aw ? oi2 : i2;
            const bool bw = (c1v > c2v) || (c1v == c2v && c1i < c2i);
            v1 = nv1; i1 = ni1;
            v2 = bw ? c1v : c2v; i2 = bw ? c1i : c2i;
            v3 = nv3;
        }
        if (lr == 0) {
            const long t = t0 + a * 16 + lg * 4 + r;
            const float e  = expf(v2 - v1);
            const float dn = 1.0f + e;
            out[t * 2 + 0] = (float)i1;
            out[t * 2 + 1] = (float)i2;
            out[(long)T_TOKENS * 2 + t * 2 + 0] = 1.0f / dn;
            out[(long)T_TOKENS * 2 + t * 2 + 1] = e / dn;
            if (v1 - v2 < EPS_GAP || v2 - v3 < EPS_GAP) {
                const unsigned p = atomicAdd(wcnt, 1u);
                if (p < cap) wlist[p] = (unsigned)t;
            }
        }
    }
}

// ---- Kernel 2: exact-chain fixup, 4 waves/token (one per OpenBLAS panel) --
// Exact OpenBLAS-SKYLAKEX chain (verified R7+): panels 320/320/192/192,
// ascending-k fp32 FMA chain per panel, sequential rounded folds.
__global__ __launch_bounds__(256)
void router_fixup(const float* __restrict__ x, const float* __restrict__ W,
                  float* __restrict__ out, const unsigned* __restrict__ wcnt,
                  const unsigned* __restrict__ wlist, unsigned cap)
{
    __shared__ float ps[4][64];
    unsigned cnt = wcnt[0]; if (cnt > cap) cnt = cap;
    const int wv = threadIdx.x >> 6;   // panel id
    const int l  = threadIdx.x & 63;   // expert
    const int kb = (wv == 0) ? 0 : (wv == 1) ? 320 : (wv == 2) ? 640 : 832;
    const int ke = (wv == 0) ? 320 : (wv == 1) ? 640 : (wv == 2) ? 832 : 1024;

    for (unsigned it = blockIdx.x; it < cnt; it += gridDim.x) {
        const long t = (long)wlist[it];
        const float* xr = x + t * (long)D;
        const float* wr = W + (long)l * D;
        float accP = 0.f;
#pragma unroll 4
        for (int k = kb; k < ke; k += 4) {
            const float4 xv = *(const float4*)(xr + k);
            const float4 wvv = *(const float4*)(wr + k);
            accP = fmaf(xv.x, wvv.x, accP);
            accP = fmaf(xv.y, wvv.y, accP);
            accP = fmaf(xv.z, wvv.z, accP);
            accP = fmaf(xv.w, wvv.w, accP);
        }
        ps[wv][l] = accP;
        __syncthreads();
        if (wv == 0) {
            const float accT = __fadd_rn(__fadd_rn(__fadd_rn(ps[0][l], ps[1][l]), ps[2][l]), ps[3][l]);
            float v1 = accT; int i1 = l;
            float v2 = -INFINITY; int i2 = 1 << 20;
#pragma unroll
            for (int m = 32; m >= 1; m >>= 1) {
                const float ov1 = __shfl_xor(v1, m);
                const int   oi1 = __shfl_xor(i1, m);
                const float ov2 = __shfl_xor(v2, m);
                const int   oi2 = __shfl_xor(i2, m);
                const bool aw = (ov1 > v1) || (ov1 == v1 && oi1 < i1);
                const float nv1 = aw ? ov1 : v1; const int ni1 = aw ? oi1 : i1;
                const float c1v = aw ? v1  : ov1; const int c1i = aw ? i1  : oi1;
                const float c2v = aw ? ov2 : v2;  const int c2i = aw ? oi2 : i2;
                const bool bw = (c1v > c2v) || (c1v == c2v && c1i < c2i);
                v1 = nv1; i1 = ni1;
                v2 = bw ? c1v : c2v; i2 = bw ? c1i : c2i;
            }
            if (l == 0) {
                const float e  = expf(v2 - v1);
                const float dn = 1.0f + e;
                out[t * 2 + 0] = (float)i1;
                out[t * 2 + 1] = (float)i2;
                out[(long)T_TOKENS * 2 + t * 2 + 0] = 1.0f / dn;
                out[(long)T_TOKENS * 2 + t * 2 + 1] = e / dn;
            }
        }
        __syncthreads();
    }
}

extern "C" void kernel_launch(void* const* d_in, const int* in_sizes, int n_in,
                              void* d_out, int out_size, void* d_ws, size_t ws_size,
                              hipStream_t stream) {
    const float* x = (const float*)d_in[0];
    const float* W = (const float*)d_in[1];
    float* out = (float*)d_out;

    // workspace layout: [0,64) wcnt | [1024, 1024+256K) W frag planes | wlist
    unsigned* wcnt  = (unsigned*)d_ws;
    bf16x8*   wpl   = (bf16x8*)((char*)d_ws + 1024);
    unsigned* wlist = (unsigned*)((char*)d_ws + 1024 + 262144);
    size_t rem = (ws_size - 1024 - 262144) / 4;
    unsigned cap = (unsigned)(rem > (1u << 22) ? (1u << 22) : rem);

    (void)hipMemsetAsync(d_ws, 0, 64, stream);
    prep_w<<<dim3(32), dim3(256), 0, stream>>>(W, wpl);
    router_mfma<<<dim3(T_TOKENS / 128), dim3(256), 0, stream>>>(x, wpl, out, wcnt, wlist, cap);
    router_fixup<<<dim3(512), dim3(256), 0, stream>>>(x, W, out, wcnt, wlist, cap);
}

// Round 23
// 160.737 us; speedup vs baseline: 1.8358x; 1.0106x over previous
//
#include <hip/hip_runtime.h>
#include <math.h>

// Problem constants: T=131072, D_IN=1024, NE=64, top_k=2
constexpr int T_TOKENS = 131072;
constexpr int D        = 1024;
constexpr float EPS_GAP = 2e-4f;   // flag threshold (>=14 sigma of ~1.4e-5 RMS split err)

typedef __attribute__((ext_vector_type(8))) short bf16x8;
typedef __attribute__((ext_vector_type(4))) float f32x4;
typedef __bf16 bf16v8 __attribute__((ext_vector_type(8)));
typedef float  f32v8  __attribute__((ext_vector_type(8)));

// split 8 fp32 into two bf16 planes (RNE): f ~= p0 + p1
__device__ __forceinline__ void split2(const float4 lo, const float4 hi,
                                       bf16x8& p0, bf16x8& p1) {
    f32v8 f = {lo.x, lo.y, lo.z, lo.w, hi.x, hi.y, hi.z, hi.w};
    bf16v8 h0 = __builtin_convertvector(f, bf16v8);
    f32v8 back = __builtin_convertvector(h0, f32v8);
    bf16v8 h1 = __builtin_convertvector(f - back, bf16v8);
    p0 = __builtin_bit_cast(bf16x8, h0);
    p1 = __builtin_bit_cast(bf16x8, h1);
}

// ---- Kernel 0: pre-split W into fragment-layout bf16 planes (256 KB) ------
// wpl[g*512 + (c*2+p)*64 + l] = plane_p( W[c*16 + (l&15)][g*32 + (l>>4)*8 .. +8] )
__global__ void prep_w(const float* __restrict__ W, bf16x8* __restrict__ wpl) {
    const int g = blockIdx.x;          // 0..31 (K window of 32)
    const int c = threadIdx.x >> 6;    // 0..3
    const int l = threadIdx.x & 63;
    const int e  = c * 16 + (l & 15);
    const int k0 = g * 32 + (l >> 4) * 8;
    const float4 lo = *(const float4*)(W + (long)e * D + k0);
    const float4 hi = *(const float4*)(W + (long)e * D + k0 + 4);
    bf16x8 p0, p1; split2(lo, hi, p0, p1);
    const int base = ((g * 4 + c) * 2) * 64 + l;
    wpl[base]      = p0;
    wpl[base + 64] = p1;
}

// ---- Kernel 1: wave-private LDS-staged MFMA router, counted-vmcnt sync ----
// 1024 blocks x 256 thr (4 waves, fully independent; NO __syncthreads).
// Wave = 32 tokens x 64 experts. A: 256B-contiguous-per-row chunks (KSTEP=64)
// staged via global_load_lds into DISTINCT double-buffer LDS OBJECTS
// (Xs0 / Xs1) with compile-time buffer identity everywhere -- the backend's
// LDS-DMA alias tracking can then prove stage(s+1) (other object) doesn't
// alias the ds_reads of chunk s, eliminating the compiler's conservative
// s_waitcnt vmcnt(0) drain per chunk (R22 used one runtime-indexed object).
// Sync = counted s_waitcnt vmcnt(24) only.
__global__ __launch_bounds__(256, 2)
void router_mfma(const float* __restrict__ x, const bf16x8* __restrict__ wpl,
                 float* __restrict__ out, unsigned* __restrict__ wcnt,
                 unsigned* __restrict__ wlist, unsigned cap)
{
    __shared__ __align__(16) char Xs0[4][8192];   // buffer 0: [wave][32 rows x 256B]
    __shared__ __align__(16) char Xs1[4][8192];   // buffer 1

    const int tid = threadIdx.x;
    const int wv  = tid >> 6;
    const int l   = tid & 63;
    const int lg  = l >> 4;       // k-octet
    const int lr  = l & 15;       // A row within tile / expert within ctile
    const long t0 = (long)blockIdx.x * 128 + wv * 32;
    const int swz = (lr & 7) << 4;

    f32x4 acc[2][4];
#pragma unroll
    for (int a = 0; a < 2; ++a)
#pragma unroll
        for (int c = 0; c < 4; ++c) acc[a][c] = f32x4{0.f, 0.f, 0.f, 0.f};

    // staging geometry: instruction i covers rows 4i..4i+3; lane covers
    // bytes [(l&15)*16, +16) of row (4i + (l>>4))'s 256B chunk window.
    const int sil = (l & 15) * 16;
    const int sir = l >> 4;
    const char* xb = (const char*)x;

#define STAGE(S, ARR)                                                          \
    {                                                                          \
        _Pragma("unroll")                                                      \
        for (int i = 0; i < 8; ++i) {                                          \
            const int rr = 4 * i + sir;                                        \
            const char* src = xb + (t0 + rr) * 4096L + (S) * 256               \
                              + (sil ^ ((rr & 7) << 4));                       \
            char* dst = &ARR[wv][i * 1024];                                    \
            __builtin_amdgcn_global_load_lds(                                  \
                (const __attribute__((address_space(1))) void*)src,            \
                (__attribute__((address_space(3))) void*)dst, 16, 0, 0);       \
        }                                                                      \
    }

#define LOADW(DST, G)                                                          \
    {                                                                          \
        _Pragma("unroll")                                                      \
        for (int c = 0; c < 4; ++c) {                                          \
            DST[c * 2 + 0] = wpl[(size_t)(G) * 512 + (c * 2 + 0) * 64 + l];    \
            DST[c * 2 + 1] = wpl[(size_t)(G) * 512 + (c * 2 + 1) * 64 + l];    \
        }                                                                      \
    }

#define SUBSTEP(ARR, SUB, W)                                                   \
    {                                                                          \
        const char* wb = &ARR[wv][0];                                          \
        const int c0 = (SUB) * 128 + lg * 32;                                  \
        const float4 lo0 = *(const float4*)(wb + lr * 256 + ((c0) ^ swz));     \
        const float4 hi0 = *(const float4*)(wb + lr * 256 + ((c0 + 16) ^ swz));\
        const float4 lo1 = *(const float4*)(wb + (16 + lr) * 256 + ((c0) ^ swz));     \
        const float4 hi1 = *(const float4*)(wb + (16 + lr) * 256 + ((c0 + 16) ^ swz));\
        bf16x8 a00, a01, a10, a11;                                             \
        split2(lo0, hi0, a00, a01);                                            \
        split2(lo1, hi1, a10, a11);                                            \
        _Pragma("unroll")                                                      \
        for (int c = 0; c < 4; ++c) {                                          \
            acc[0][c] = __builtin_amdgcn_mfma_f32_16x16x32_bf16(a00, W[c*2+0], acc[0][c], 0, 0, 0); \
            acc[0][c] = __builtin_amdgcn_mfma_f32_16x16x32_bf16(a01, W[c*2+0], acc[0][c], 0, 0, 0); \
            acc[0][c] = __builtin_amdgcn_mfma_f32_16x16x32_bf16(a00, W[c*2+1], acc[0][c], 0, 0, 0); \
            acc[1][c] = __builtin_amdgcn_mfma_f32_16x16x32_bf16(a10, W[c*2+0], acc[1][c], 0, 0, 0); \
            acc[1][c] = __builtin_amdgcn_mfma_f32_16x16x32_bf16(a11, W[c*2+0], acc[1][c], 0, 0, 0); \
            acc[1][c] = __builtin_amdgcn_mfma_f32_16x16x32_bf16(a10, W[c*2+1], acc[1][c], 0, 0, 0); \
        }                                                                      \
    }

    STAGE(0, Xs0);

#pragma unroll 1
    for (int sp = 0; sp < 8; ++sp) {
        const int sA = 2 * sp;
        const int sB = 2 * sp + 1;
        // ---- chunk sA: compute from Xs0, stage sB into Xs1 ----
        {
            bf16x8 w0[8], w1[8];
            LOADW(w0, 2 * sA)
            LOADW(w1, 2 * sA + 1)
            STAGE(sB, Xs1);
            // outstanding: W:16 + stage(sB):8 + stage(sA):8(oldest) = 32
            // -> vmcnt(24) retires exactly stage(sA)
            asm volatile("s_waitcnt vmcnt(24)" ::: "memory");
            __builtin_amdgcn_sched_barrier(0);
            SUBSTEP(Xs0, 0, w0)
            SUBSTEP(Xs0, 1, w1)
        }
        // ---- chunk sB: compute from Xs1, stage sA+2 into Xs0 ----
        {
            bf16x8 w0[8], w1[8];
            LOADW(w0, 2 * sB)
            LOADW(w1, 2 * sB + 1)
            const int sn = (sB + 1 < 16) ? sB + 1 : 15;   // clamped redundant
            STAGE(sn, Xs0);
            asm volatile("s_waitcnt vmcnt(24)" ::: "memory");
            __builtin_amdgcn_sched_barrier(0);
            SUBSTEP(Xs1, 0, w0)
            SUBSTEP(Xs1, 1, w1)
        }
    }
#undef SUBSTEP
#undef LOADW
#undef STAGE

    // ---- epilogue: top-3 per token, provisional write + gap-flag ----
    // C/D: col = lane&15 (expert in ctile), row = (lane>>4)*4 + reg (token)
#pragma unroll
    for (int a = 0; a < 2; ++a)
#pragma unroll
    for (int r = 0; r < 4; ++r) {
        float v1 = acc[a][0][r]; int i1 = lr;
        float v2 = -INFINITY;    int i2 = 1 << 20;
        float v3 = -INFINITY;
#pragma unroll
        for (int c = 1; c < 4; ++c) {
            const float v = acc[a][c][r]; const int e = lr + 16 * c;
            if (v > v1)      { v3 = v2; v2 = v1; i2 = i1; v1 = v; i1 = e; }
            else if (v > v2) { v3 = v2; v2 = v;  i2 = e; }
            else if (v > v3) { v3 = v; }
        }
#pragma unroll
        for (int m = 8; m >= 1; m >>= 1) {
            const float ov1 = __shfl_xor(v1, m);
            const int   oi1 = __shfl_xor(i1, m);
            const float ov2 = __shfl_xor(v2, m);
            const int   oi2 = __shfl_xor(i2, m);
            const float ov3 = __shfl_xor(v3, m);
            const bool tv = v1 >= ov1;
            const float x2 = tv ? v2 : ov2, x3 = tv ? v3 : ov3;
            const float y1 = tv ? ov1 : v1, y2 = tv ? ov2 : v2;
            const float nv3 = (x2 >= y1) ? fmaxf(x3, y1) : fmaxf(x2, y2);
            const bool aw = (ov1 > v1) || (ov1 == v1 && oi1 < i1);
            const float nv1 = aw ? ov1 : v1; const int ni1 = aw ? oi1 : i1;
            const float c1v = aw ? v1  : ov1; const int c1i = aw ? i1  : oi1;
            const float c2v = aw ? ov2 : v2;  const int c2i = aw ? oi2 : i2;
            const bool bw = (c1v > c2v) || (c1v == c2v && c1i < c2i);
            v1 = nv1; i1 = ni1;
            v2 = bw ? c1v : c2v; i2 = bw ? c1i : c2i;
            v3 = nv3;
        }
        if (lr == 0) {
            const long t = t0 + a * 16 + lg * 4 + r;
            const float e  = expf(v2 - v1);
            const float dn = 1.0f + e;
            out[t * 2 + 0] = (float)i1;
            out[t * 2 + 1] = (float)i2;
            out[(long)T_TOKENS * 2 + t * 2 + 0] = 1.0f / dn;
            out[(long)T_TOKENS * 2 + t * 2 + 1] = e / dn;
            if (v1 - v2 < EPS_GAP || v2 - v3 < EPS_GAP) {
                const unsigned p = atomicAdd(wcnt, 1u);
                if (p < cap) wlist[p] = (unsigned)t;
            }
        }
    }
}

// ---- Kernel 2: exact-chain fixup, 4 waves/token (one per OpenBLAS panel) --
// Exact OpenBLAS-SKYLAKEX chain (verified R7+): panels 320/320/192/192,
// ascending-k fp32 FMA chain per panel, sequential rounded folds.
__global__ __launch_bounds__(256)
void router_fixup(const float* __restrict__ x, const float* __restrict__ W,
                  float* __restrict__ out, const unsigned* __restrict__ wcnt,
                  const unsigned* __restrict__ wlist, unsigned cap)
{
    __shared__ float ps[4][64];
    unsigned cnt = wcnt[0]; if (cnt > cap) cnt = cap;
    const int wv = threadIdx.x >> 6;   // panel id
    const int l  = threadIdx.x & 63;   // expert
    const int kb = (wv == 0) ? 0 : (wv == 1) ? 320 : (wv == 2) ? 640 : 832;
    const int ke = (wv == 0) ? 320 : (wv == 1) ? 640 : (wv == 2) ? 832 : 1024;

    for (unsigned it = blockIdx.x; it < cnt; it += gridDim.x) {
        const long t = (long)wlist[it];
        const float* xr = x + t * (long)D;
        const float* wr = W + (long)l * D;
        float accP = 0.f;
#pragma unroll 4
        for (int k = kb; k < ke; k += 4) {
            const float4 xv = *(const float4*)(xr + k);
            const float4 wvv = *(const float4*)(wr + k);
            accP = fmaf(xv.x, wvv.x, accP);
            accP = fmaf(xv.y, wvv.y, accP);
            accP = fmaf(xv.z, wvv.z, accP);
            accP = fmaf(xv.w, wvv.w, accP);
        }
        ps[wv][l] = accP;
        __syncthreads();
        if (wv == 0) {
            const float accT = __fadd_rn(__fadd_rn(__fadd_rn(ps[0][l], ps[1][l]), ps[2][l]), ps[3][l]);
            float v1 = accT; int i1 = l;
            float v2 = -INFINITY; int i2 = 1 << 20;
#pragma unroll
            for (int m = 32; m >= 1; m >>= 1) {
                const float ov1 = __shfl_xor(v1, m);
                const int   oi1 = __shfl_xor(i1, m);
                const float ov2 = __shfl_xor(v2, m);
                const int   oi2 = __shfl_xor(i2, m);
                const bool aw = (ov1 > v1) || (ov1 == v1 && oi1 < i1);
                const float nv1 = aw ? ov1 : v1; const int ni1 = aw ? oi1 : i1;
                const float c1v = aw ? v1  : ov1; const int c1i = aw ? i1  : oi1;
                const float c2v = aw ? ov2 : v2;  const int c2i = aw ? oi2 : i2;
                const bool bw = (c1v > c2v) || (c1v == c2v && c1i < c2i);
                v1 = nv1; i1 = ni1;
                v2 = bw ? c1v : c2v; i2 = bw ? c1i : c2i;
            }
            if (l == 0) {
                const float e  = expf(v2 - v1);
                const float dn = 1.0f + e;
                out[t * 2 + 0] = (float)i1;
                out[t * 2 + 1] = (float)i2;
                out[(long)T_TOKENS * 2 + t * 2 + 0] = 1.0f / dn;
                out[(long)T_TOKENS * 2 + t * 2 + 1] = e / dn;
            }
        }
        __syncthreads();
    }
}

extern "C" void kernel_launch(void* const* d_in, const int* in_sizes, int n_in,
                              void* d_out, int out_size, void* d_ws, size_t ws_size,
                              hipStream_t stream) {
    const float* x = (const float*)d_in[0];
    const float* W = (const float*)d_in[1];
    float* out = (float*)d_out;

    // workspace layout: [0,64) wcnt | [1024, 1024+256K) W frag planes | wlist
    unsigned* wcnt  = (unsigned*)d_ws;
    bf16x8*   wpl   = (bf16x8*)((char*)d_ws + 1024);
    unsigned* wlist = (unsigned*)((char*)d_ws + 1024 + 262144);
    size_t rem = (ws_size - 1024 - 262144) / 4;
    unsigned cap = (unsigned)(rem > (1u << 22) ? (1u << 22) : rem);

    (void)hipMemsetAsync(d_ws, 0, 64, stream);
    prep_w<<<dim3(32), dim3(256), 0, stream>>>(W, wpl);
    router_mfma<<<dim3(T_TOKENS / 128), dim3(256), 0, stream>>>(x, wpl, out, wcnt, wlist, cap);
    router_fixup<<<dim3(512), dim3(256), 0, stream>>>(x, W, out, wcnt, wlist, cap);
}